// Round 3
// baseline (418.144 us; speedup 1.0000x reference)
//
#include <hip/hip_runtime.h>
#include <hip/hip_bf16.h>
#include <cstdint>
#include <cstddef>

// ---- problem constants ----
constexpr int LQc = 1024, LKc = 1024, Bc = 8, Ec = 1024, Hc = 16, Dc = 64;

typedef __bf16 bf16;
typedef __bf16 bf16x4 __attribute__((ext_vector_type(4)));
typedef __bf16 bf16x8 __attribute__((ext_vector_type(8)));
typedef float  f32x4  __attribute__((ext_vector_type(4)));

#define MFMA16(a, b, c) __builtin_amdgcn_mfma_f32_16x16x32_bf16((a), (b), (c), 0, 0, 0)

__device__ __forceinline__ void gload_lds16(const bf16* g, bf16* l) {
  __builtin_amdgcn_global_load_lds((const __attribute__((address_space(1))) void*)g,
                                   (__attribute__((address_space(3))) void*)l, 16, 0, 0);
}

// ============================================================================
// Convert f32 inputs -> bf16, concatenated into ws.
// ============================================================================
__global__ __launch_bounds__(256) void k_convert(const float* __restrict__ q,
                                                 const float* __restrict__ k,
                                                 const float* __restrict__ wq,
                                                 const float* __restrict__ wkv,
                                                 const float* __restrict__ wout,
                                                 bf16* __restrict__ dst) {
  const size_t i = ((size_t)blockIdx.x * 256 + threadIdx.x) * 8;
  const float* src; size_t off;
  if (i < 8388608)        { src = q;    off = i; }
  else if (i < 16777216)  { src = k;    off = i - 8388608; }
  else if (i < 17825792)  { src = wq;   off = i - 16777216; }
  else if (i < 19922944)  { src = wkv;  off = i - 17825792; }
  else                    { src = wout; off = i - 19922944; }
  const f32x4 a = *reinterpret_cast<const f32x4*>(src + off);
  const f32x4 b = *reinterpret_cast<const f32x4*>(src + off + 4);
  bf16x8 o;
  o[0] = (bf16)a.x; o[1] = (bf16)a.y; o[2] = (bf16)a.z; o[3] = (bf16)a.w;
  o[4] = (bf16)b.x; o[5] = (bf16)b.y; o[6] = (bf16)b.z; o[7] = (bf16)b.w;
  *reinterpret_cast<bf16x8*>(dst + i) = o;
}

// ============================================================================
// Pipelined bf16 GEMM: block 256(tokens) x 128(features), K=1024, BK=32.
// 4 waves (2x2), wave tile 128x64 = 8x4 frags of 16x16x32.
// Depth-2 pipeline: 2 LDS buffers, counted vmcnt(6), raw barriers,
// XOR-chunk-swizzled LDS (c ^= (row>>1)&3) via pre-swizzled global source.
// MODE 0 (fused proj): by 0-7 -> Qh (x0.125), 8-15 -> Kh, 16-23 -> Vh
// MODE 2 (out proj):   f32 row-major to o_f
// ============================================================================
#define STAGEG(P, K0)                                                         \
  {                                                                           \
    gload_lds16(pa0 + (K0), sbuf + (P) * 12288 + wave * 2048 + 0 * 512);      \
    gload_lds16(pa1 + (K0), sbuf + (P) * 12288 + wave * 2048 + 1 * 512);      \
    gload_lds16(pa2 + (K0), sbuf + (P) * 12288 + wave * 2048 + 2 * 512);      \
    gload_lds16(pa3 + (K0), sbuf + (P) * 12288 + wave * 2048 + 3 * 512);      \
    gload_lds16(pb0 + (K0), sbuf + (P) * 12288 + 8192 + wave * 1024 + 0 * 512); \
    gload_lds16(pb1 + (K0), sbuf + (P) * 12288 + 8192 + wave * 1024 + 1 * 512); \
  }

#define GBODY(P, VMASM, DOSTAGE)                                              \
  {                                                                           \
    asm volatile(VMASM ::: "memory");                                         \
    __builtin_amdgcn_s_barrier();                                             \
    __builtin_amdgcn_sched_barrier(0);                                        \
    bf16x8 af[8], bff[4];                                                     \
    _Pragma("unroll") for (int m = 0; m < 8; ++m)                             \
        af[m] = *reinterpret_cast<const bf16x8*>(                             \
            smem + (P) * 24576 + wm * 8192 + m * 1024 + addr_v);              \
    _Pragma("unroll") for (int n = 0; n < 4; ++n)                             \
        bff[n] = *reinterpret_cast<const bf16x8*>(                            \
            smem + (P) * 24576 + 16384 + wn * 4096 + n * 1024 + addr_v);      \
    asm volatile("s_waitcnt lgkmcnt(0)" ::: "memory");                        \
    __builtin_amdgcn_s_barrier();                                             \
    __builtin_amdgcn_sched_barrier(0);                                        \
    if (DOSTAGE) { STAGEG(P, k0); k0 += 32; }                                 \
    __builtin_amdgcn_s_setprio(1);                                            \
    _Pragma("unroll") for (int m = 0; m < 8; ++m)                             \
        _Pragma("unroll") for (int n = 0; n < 4; ++n)                         \
            acc[m][n] = MFMA16(af[m], bff[n], acc[m][n]);                     \
    __builtin_amdgcn_s_setprio(0);                                            \
  }

template <int MODE>
__global__ __launch_bounds__(256, 2) void k_gemm(const bf16* __restrict__ Aq,
                                                 const bf16* __restrict__ Ak,
                                                 const bf16* __restrict__ Wq,
                                                 const bf16* __restrict__ Wkv,
                                                 bf16* __restrict__ qh,
                                                 bf16* __restrict__ kh,
                                                 bf16* __restrict__ vh,
                                                 float* __restrict__ o_f) {
  __shared__ char smem_raw[49152];  // 2 buffers x (A 16KB + B 8KB)
  char* smem = smem_raw;
  bf16* sbuf = (bf16*)smem_raw;

  const int tid = threadIdx.x, lane = tid & 63, wave = tid >> 6;
  const int wm = wave & 1, wn = wave >> 1;
  const int fr = lane & 15;

  // XCD swizzle (gridDim.x % 8 == 0), by-major chunks
  const int cpx = gridDim.x >> 3;
  const int logical = (blockIdx.x & 7) * cpx + (blockIdx.x >> 3);
  const int bx = logical & 31, by = logical >> 5;
  const int m0 = bx * 256;

  const bf16* Ap;
  const bf16* Wp;
  if constexpr (MODE == 0) {
    Ap = (by < 8) ? Aq : Ak;
    Wp = (by < 8) ? (Wq + (size_t)by * 131072) : (Wkv + (size_t)(by - 8) * 131072);
  } else {
    Ap = Aq;
    Wp = Wq + (size_t)by * 131072;
  }

  // staging source pointers (pre-swizzled chunk: c = (l&3) ^ ((l>>3)&3))
  const int l4 = lane >> 2;
  const int sc = ((lane & 3) ^ ((lane >> 3) & 3)) * 8;  // elem offset
  const bf16* pa0 = Ap + (size_t)(m0 + wave * 64 + 0 * 16 + l4) * Ec + sc;
  const bf16* pa1 = Ap + (size_t)(m0 + wave * 64 + 1 * 16 + l4) * Ec + sc;
  const bf16* pa2 = Ap + (size_t)(m0 + wave * 64 + 2 * 16 + l4) * Ec + sc;
  const bf16* pa3 = Ap + (size_t)(m0 + wave * 64 + 3 * 16 + l4) * Ec + sc;
  const bf16* pb0 = Wp + (size_t)(wave * 32 + 0 * 16 + l4) * Ec + sc;
  const bf16* pb1 = Wp + (size_t)(wave * 32 + 1 * 16 + l4) * Ec + sc;

  // fragment read byte offset (swizzled): fr*64 + ((q ^ ((fr>>1)&3))<<4)
  const int q4 = lane >> 4;
  const int addr_v = fr * 64 + ((q4 ^ ((fr >> 1) & 3)) << 4);

  f32x4 acc[8][4] = {};

  int k0 = 64;
  STAGEG(0, 0);
  STAGEG(1, 32);
  for (int it = 0; it < 15; ++it) {
    GBODY(0, "s_waitcnt vmcnt(6)", true);
    GBODY(1, "s_waitcnt vmcnt(6)", true);
  }
  GBODY(0, "s_waitcnt vmcnt(6)", false);
  GBODY(1, "s_waitcnt vmcnt(0)", false);

  // epilogue; C/D frag: col = lane&15, row = (lane>>4)*4 + r
  const int rb = (lane >> 4) * 4;
#pragma unroll
  for (int m = 0; m < 8; ++m) {
#pragma unroll
    for (int n = 0; n < 4; ++n) {
#pragma unroll
      for (int r = 0; r < 4; ++r) {
        const int tok = m0 + wm * 128 + m * 16 + rb + r;
        const int col = wn * 64 + n * 16 + fr;
        const float val = acc[m][n][r];
        if constexpr (MODE == 0) {
          const int lq = tok >> 3, bb = tok & 7;
          if (by < 8) {
            const int f = by * 128 + col, h = f >> 6, dd = f & 63;
            qh[(((size_t)(bb * Hc + h)) * LQc + lq) * Dc + dd] = (bf16)(val * 0.125f);
          } else if (by < 16) {
            const int f = (by - 8) * 128 + col, h = f >> 6, dd = f & 63;
            kh[(((size_t)(bb * Hc + h)) * LKc + lq) * Dc + dd] = (bf16)val;
          } else {
            const int f = (by - 16) * 128 + col, h = f >> 6, dd = f & 63;
            vh[(((size_t)(bb * Hc + h)) * LKc + lq) * Dc + dd] = (bf16)val;
          }
        } else {
          o_f[(size_t)tok * Ec + by * 128 + col] = val;
        }
      }
    }
  }
}

// ============================================================================
// Transpose Vh[bh][lk][64] -> VhT[bh][64][lk], 64x64 LDS tiles
// ============================================================================
__global__ __launch_bounds__(256) void k_vtrans(const bf16* __restrict__ Vh,
                                                bf16* __restrict__ VhT) {
  __shared__ bf16 tile[64][72];
  const int bh = blockIdx.y;
  const int l0 = blockIdx.x * 64;
  const int r = threadIdx.x >> 3, c = (threadIdx.x & 7) * 8;
#pragma unroll
  for (int rr = 0; rr < 2; ++rr) {
    const int row = rr * 32 + r;
    *reinterpret_cast<bf16x8*>(&tile[row][c]) =
        *reinterpret_cast<const bf16x8*>(Vh + ((size_t)bh * LKc + l0 + row) * Dc + c);
  }
  __syncthreads();
#pragma unroll
  for (int rr = 0; rr < 2; ++rr) {
    const int d = rr * 32 + r;
    bf16x8 o;
#pragma unroll
    for (int j = 0; j < 8; ++j) o[j] = tile[c + j][d];
    *reinterpret_cast<bf16x8*>(VhT + ((size_t)bh * Dc + d) * LKc + l0 + c) = o;
  }
}

// ============================================================================
// Attention: block = (b,h) x 32 q-rows, 4 waves. QK^T -> exp(f32 score) -> e
// in LDS (bf16) + per-lane sums -> 1/sum; then INTERLEAVED {f32 prob write
// row s || PV MFMA step kc=s*32}; ctx scaled by 1/sum in epilogue.
// ============================================================================
__global__ __launch_bounds__(256) void k_attn(const bf16* __restrict__ Qh,
                                              const bf16* __restrict__ Kh,
                                              const bf16* __restrict__ VhT,
                                              const int* __restrict__ mask,
                                              float* __restrict__ attn_out,
                                              bf16* __restrict__ ctx_out) {
  __shared__ bf16 sP[32][1032];
  __shared__ float smask[1024];
  __shared__ float psum[4][32];
  __shared__ float rinv[32];

  const int tid = threadIdx.x;
  const int lane = tid & 63, wave = tid >> 6;

  int flat = blockIdx.x;                 // 4096 blocks
  flat = (flat & 7) * 512 + (flat >> 3); // XCD swizzle: 16 bh per XCD
  const int bh = flat >> 5;
  const int q0 = (flat & 31) * 32;
  const int b = bh >> 4, h = bh & 15;
  const int fr = lane & 15, fo = (lane >> 4) * 8, rb = (lane >> 4) * 4;

  for (int c = tid; c < 1024; c += 256)
    smask[c] = mask[b * LKc + c] ? -1e9f : 0.0f;

  // Q fragments straight from global
  bf16x8 qf[2][2];
  const bf16* Qb = Qh + ((size_t)bh * LQc + q0) * Dc;
#pragma unroll
  for (int m = 0; m < 2; ++m)
#pragma unroll
    for (int kc = 0; kc < 2; ++kc)
      qf[m][kc] = *reinterpret_cast<const bf16x8*>(Qb + (size_t)(m * 16 + fr) * Dc + kc * 32 + fo);
  __syncthreads();  // smask ready

  // ---- QK^T + exp + running sums; wave w owns cols [w*256, w*256+256) ----
  const bf16* Kb = Kh + (size_t)bh * LKc * Dc;
  float s0[4] = {0.f, 0.f, 0.f, 0.f}, s1[4] = {0.f, 0.f, 0.f, 0.f};
  for (int t = 0; t < 16; ++t) {
    const int n = (wave * 16 + t) * 16;
    const bf16* kp = Kb + (size_t)(n + fr) * Dc + fo;
    const bf16x8 kf0 = *reinterpret_cast<const bf16x8*>(kp);
    const bf16x8 kf1 = *reinterpret_cast<const bf16x8*>(kp + 32);
    f32x4 c0 = {}, c1 = {};
    __builtin_amdgcn_s_setprio(1);
    c0 = MFMA16(qf[0][0], kf0, c0);
    c0 = MFMA16(qf[0][1], kf1, c0);
    c1 = MFMA16(qf[1][0], kf0, c1);
    c1 = MFMA16(qf[1][1], kf1, c1);
    __builtin_amdgcn_s_setprio(0);
    const int col = n + fr;
    const float madd = smask[col];
#pragma unroll
    for (int r = 0; r < 4; ++r) {
      const float e0 = __expf(c0[r] + madd);
      const float e1 = __expf(c1[r] + madd);
      s0[r] += e0; s1[r] += e1;
      sP[rb + r][col]      = (bf16)e0;
      sP[16 + rb + r][col] = (bf16)e1;
    }
  }
#pragma unroll
  for (int o = 1; o < 16; o <<= 1)
#pragma unroll
    for (int r = 0; r < 4; ++r) {
      s0[r] += __shfl_xor(s0[r], o, 64);
      s1[r] += __shfl_xor(s1[r], o, 64);
    }
  if (fr == 0) {
#pragma unroll
    for (int r = 0; r < 4; ++r) {
      psum[wave][rb + r]      = s0[r];
      psum[wave][16 + rb + r] = s1[r];
    }
  }
  __syncthreads();
  if (tid < 32)
    rinv[tid] = 1.0f / (psum[0][tid] + psum[1][tid] + psum[2][tid] + psum[3][tid]);
  __syncthreads();

  // ---- interleaved: f32 prob write (row s) || PV MFMA (kc = s*32) ----
  float* ap = attn_out + ((size_t)bh * LQc + q0) * LKc;
  const bf16* Vb = VhT + ((size_t)bh * Dc + wave * 16 + fr) * LKc;
  f32x4 cacc0 = {}, cacc1 = {};
  for (int s = 0; s < 32; ++s) {
    const int kc = s * 32;
    const bf16x8 vf  = *reinterpret_cast<const bf16x8*>(Vb + kc + fo);
    const bf16x8 pa0 = *reinterpret_cast<const bf16x8*>(&sP[fr][kc + fo]);
    const bf16x8 pa1 = *reinterpret_cast<const bf16x8*>(&sP[16 + fr][kc + fo]);
    __builtin_amdgcn_s_setprio(1);
    cacc0 = MFMA16(pa0, vf, cacc0);
    cacc1 = MFMA16(pa1, vf, cacc1);
    __builtin_amdgcn_s_setprio(0);
    const float rs = rinv[s];
    const bf16x4 v = *reinterpret_cast<const bf16x4*>(&sP[s][tid * 4]);
    f32x4 p;
    p.x = (float)v.x * rs; p.y = (float)v.y * rs;
    p.z = (float)v.z * rs; p.w = (float)v.w * rs;
    *reinterpret_cast<f32x4*>(ap + (size_t)s * LKc + tid * 4) = p;
  }

  const int e = h * Dc + wave * 16 + fr;
#pragma unroll
  for (int r = 0; r < 4; ++r) {
    const int qa = q0 + rb + r;
    ctx_out[((size_t)qa * Bc + b) * Ec + e] = (bf16)(cacc0[r] * rinv[rb + r]);
    const int qb2 = q0 + 16 + rb + r;
    ctx_out[((size_t)qb2 * Bc + b) * Ec + e] = (bf16)(cacc1[r] * rinv[16 + rb + r]);
  }
}

// ============================================================================
extern "C" void kernel_launch(void* const* d_in, const int* in_sizes, int n_in,
                              void* d_out, int out_size, void* d_ws, size_t ws_size,
                              hipStream_t stream) {
  const float* query = (const float*)d_in[0];
  const float* keyx  = (const float*)d_in[1];
  const int*   mask  = (const int*)d_in[2];
  const float* wq    = (const float*)d_in[3];
  const float* wkv   = (const float*)d_in[4];
  const float* wout  = (const float*)d_in[5];

  float* out  = (float*)d_out;                  // (LQ,B,E) flat
  float* attn = out + (size_t)LQc * Bc * Ec;    // (B,H,LQ,LK) flat

  bf16* cvt   = (bf16*)d_ws;
  bf16* qb    = cvt;                    // 8,388,608
  bf16* kb    = qb   + 8388608;         // 8,388,608
  bf16* wqb   = kb   + 8388608;         // 1,048,576
  bf16* wkvb  = wqb  + 1048576;         // 2,097,152
  bf16* woutb = wkvb + 2097152;         // 1,048,576
  bf16* qh    = woutb + 1048576;        // 8,388,608
  bf16* kh    = qh   + 8388608;         // 8,388,608
  bf16* vh    = kh   + 8388608;         // 8,388,608
  bf16* vt    = qb;                     // alias: qb dead after k_gemm<0>
  bf16* ctx   = kb;                     // alias: kb dead after k_gemm<0>

  k_convert<<<10240, 256, 0, stream>>>(query, keyx, wq, wkv, wout, cvt);
  k_gemm<0><<<768, 256, 0, stream>>>(qb, kb, wqb, wkvb, qh, kh, vh, nullptr);
  k_vtrans<<<dim3(16, 128), 256, 0, stream>>>(vh, vt);
  k_attn<<<4096, 256, 0, stream>>>(qh, kh, vt, mask, attn, ctx);
  k_gemm<2><<<256, 256, 0, stream>>>(ctx, nullptr, woutb, nullptr, nullptr, nullptr, nullptr, out);
}

// Round 4
// 359.790 us; speedup vs baseline: 1.1622x; 1.1622x over previous
//
#include <hip/hip_runtime.h>
#include <hip/hip_bf16.h>
#include <cstdint>
#include <cstddef>

// ---- problem constants ----
constexpr int LQc = 1024, LKc = 1024, Bc = 8, Ec = 1024, Hc = 16, Dc = 64;

typedef __bf16 bf16;
typedef __bf16 bf16x4 __attribute__((ext_vector_type(4)));
typedef __bf16 bf16x8 __attribute__((ext_vector_type(8)));
typedef float  f32x4  __attribute__((ext_vector_type(4)));

#define MFMA16(a, b, c) __builtin_amdgcn_mfma_f32_16x16x32_bf16((a), (b), (c), 0, 0, 0)

__device__ __forceinline__ void gload_lds16(const bf16* g, bf16* l) {
  __builtin_amdgcn_global_load_lds((const __attribute__((address_space(1))) void*)g,
                                   (__attribute__((address_space(3))) void*)l, 16, 0, 0);
}

// ============================================================================
// Convert f32 inputs -> bf16, concatenated into ws. query scaled by 0.125
// (folds the attention scaling into the Q projection: linear).
// ============================================================================
__global__ __launch_bounds__(256) void k_convert(const float* __restrict__ q,
                                                 const float* __restrict__ k,
                                                 const float* __restrict__ wq,
                                                 const float* __restrict__ wkv,
                                                 const float* __restrict__ wout,
                                                 bf16* __restrict__ dst) {
  const size_t i = ((size_t)blockIdx.x * 256 + threadIdx.x) * 8;
  const float* src; size_t off; float sc = 1.0f;
  if (i < 8388608)        { src = q;    off = i; sc = 0.125f; }
  else if (i < 16777216)  { src = k;    off = i - 8388608; }
  else if (i < 17825792)  { src = wq;   off = i - 16777216; }
  else if (i < 19922944)  { src = wkv;  off = i - 17825792; }
  else                    { src = wout; off = i - 19922944; }
  const f32x4 a = *reinterpret_cast<const f32x4*>(src + off);
  const f32x4 b = *reinterpret_cast<const f32x4*>(src + off + 4);
  bf16x8 o;
  o[0] = (bf16)(a.x * sc); o[1] = (bf16)(a.y * sc);
  o[2] = (bf16)(a.z * sc); o[3] = (bf16)(a.w * sc);
  o[4] = (bf16)(b.x * sc); o[5] = (bf16)(b.y * sc);
  o[6] = (bf16)(b.z * sc); o[7] = (bf16)(b.w * sc);
  *reinterpret_cast<bf16x8*>(dst + i) = o;
}

// ============================================================================
// m97-structure bf16 GEMM (R2-proven inner loop): 128x128 tile, BK=32,
// 4 waves 2x2 (wave tile 64x64 = 4x4 frags), global_load_lds(16B) staging,
// simple 2-barrier K-loop (compiler-scheduled), XCD swizzle.
// MODE 0 (fused proj, 1536 blocks = 64 m x 24 n):
//   by 0-7: q2 @ Wq -> q3 | by 8-15: k2 @ Wkv[0:1024] -> k3
//   by 16-23: k2 @ Wkv[1024:2048] -> v3        (all token-major [8192][1024])
// MODE 2 (out proj, 512 blocks = 64 m x 8 n): ctx @ Wout -> f32 out
// ============================================================================
template <int MODE>
__global__ __launch_bounds__(256) void k_gemm(const bf16* __restrict__ Aq,
                                              const bf16* __restrict__ Ak,
                                              const bf16* __restrict__ Wq,
                                              const bf16* __restrict__ Wkv,
                                              bf16* __restrict__ q3,
                                              bf16* __restrict__ k3,
                                              bf16* __restrict__ v3,
                                              float* __restrict__ o_f) {
  __shared__ bf16 As[128 * 32];
  __shared__ bf16 Bs[128 * 32];

  const int tid  = threadIdx.x;
  const int lane = tid & 63, wave = tid >> 6;
  const int wm = wave & 1, wn = wave >> 1;

  // XCD-aware swizzle (grid % 8 == 0)
  const int cpx = gridDim.x >> 3;
  const int logical = (blockIdx.x & 7) * cpx + (blockIdx.x >> 3);
  const int bx = logical & 63, by = logical >> 6;
  const int m0 = bx * 128;

  const bf16* Ap;
  const bf16* Wp;
  bf16* Op = nullptr;
  if constexpr (MODE == 0) {
    if (by < 8)       { Ap = Aq; Wp = Wq  + (size_t)by * 131072;        Op = q3; }
    else if (by < 16) { Ap = Ak; Wp = Wkv + (size_t)(by - 8) * 131072;  Op = k3; }
    else              { Ap = Ak; Wp = Wkv + 1048576 + (size_t)(by - 16) * 131072; Op = v3; }
  } else {
    Ap = Aq; Wp = Wq + (size_t)by * 131072;
  }
  const int col0 = (by & 7) * 128;

  const int fr = lane & 15, fo = (lane >> 4) * 8;

  f32x4 acc[4][4] = {};

  // staging: wave stages rows [wave*32, wave*32+32), 16 rows per instruction
  const int srow = lane >> 2;          // 0..15
  const int scol = (lane & 3) * 8;     // elems
  const bf16* ga = Ap + (size_t)(m0 + wave * 32 + srow) * Ec + scol;
  const bf16* gb = Wp + (size_t)(wave * 32 + srow) * Ec + scol;
  bf16* lA = As + wave * 1024;
  bf16* lB = Bs + wave * 1024;

  for (int k0 = 0; k0 < Ec; k0 += 32) {
    gload_lds16(ga + k0, lA);
    gload_lds16(ga + k0 + 16 * Ec, lA + 512);
    gload_lds16(gb + k0, lB);
    gload_lds16(gb + k0 + 16 * Ec, lB + 512);
    __syncthreads();

    bf16x8 a[4], b[4];
#pragma unroll
    for (int i = 0; i < 4; ++i) {
      a[i] = *reinterpret_cast<const bf16x8*>(As + (wm * 64 + i * 16 + fr) * 32 + fo);
      b[i] = *reinterpret_cast<const bf16x8*>(Bs + (wn * 64 + i * 16 + fr) * 32 + fo);
    }
#pragma unroll
    for (int i = 0; i < 4; ++i)
#pragma unroll
      for (int j = 0; j < 4; ++j) acc[i][j] = MFMA16(a[i], b[j], acc[i][j]);
    __syncthreads();
  }

  // epilogue; C/D frag: col = lane&15, row = (lane>>4)*4 + r. Token-major out.
  const int rb = (lane >> 4) * 4;
#pragma unroll
  for (int i = 0; i < 4; ++i) {
#pragma unroll
    for (int j = 0; j < 4; ++j) {
      const int col = col0 + wn * 64 + j * 16 + fr;
#pragma unroll
      for (int r = 0; r < 4; ++r) {
        const int tok = m0 + wm * 64 + i * 16 + rb + r;
        const float val = acc[i][j][r];
        if constexpr (MODE == 0) {
          Op[(size_t)tok * Ec + col] = (bf16)val;
        } else {
          o_f[(size_t)tok * Ec + col] = val;
        }
      }
    }
  }
}

// ============================================================================
// Transpose v3[t=lk*8+b][h*64+d] -> VhT[bh][d][lk], 64(lk) x 64(d) LDS tiles
// ============================================================================
__global__ __launch_bounds__(256) void k_vtrans(const bf16* __restrict__ v3,
                                                bf16* __restrict__ VhT) {
  __shared__ bf16 tile[64][72];
  const int bh = blockIdx.y;
  const int b = bh >> 4, h = bh & 15;
  const int l0 = blockIdx.x * 64;
  const int r = threadIdx.x >> 3, c = (threadIdx.x & 7) * 8;
#pragma unroll
  for (int rr = 0; rr < 2; ++rr) {
    const int lk = rr * 32 + r;
    *reinterpret_cast<bf16x8*>(&tile[lk][c]) =
        *reinterpret_cast<const bf16x8*>(v3 + ((size_t)(l0 + lk) * Bc + b) * Ec + h * Dc + c);
  }
  __syncthreads();
#pragma unroll
  for (int rr = 0; rr < 2; ++rr) {
    const int d = rr * 32 + r;
    bf16x8 o;
#pragma unroll
    for (int j = 0; j < 8; ++j) o[j] = tile[c + j][d];
    *reinterpret_cast<bf16x8*>(VhT + ((size_t)bh * Dc + d) * LKc + l0 + c) = o;
  }
}

// ============================================================================
// Attention (R2-proven structure): block = (b,h) x 32 q-rows, 4 waves.
// QK^T -> exp(f32 score) -> e in LDS (bf16) + per-lane sums -> 1/sum ->
// f32 prob write + PV on e, 1/sum folded into ctx epilogue. No max pass.
// Q/K read token-major; V^T from VhT.
// ============================================================================
__global__ __launch_bounds__(256) void k_attn(const bf16* __restrict__ q3,
                                              const bf16* __restrict__ k3,
                                              const bf16* __restrict__ VhT,
                                              const int* __restrict__ mask,
                                              float* __restrict__ attn_out,
                                              bf16* __restrict__ ctx_out) {
  __shared__ bf16 sP[32][1032];
  __shared__ float smask[1024];
  __shared__ float psum[4][32];
  __shared__ float rinv[32];

  const int tid = threadIdx.x;
  const int lane = tid & 63, wave = tid >> 6;

  int flat = blockIdx.x;                 // 4096 blocks
  flat = (flat & 7) * 512 + (flat >> 3); // XCD swizzle: b == XCD
  const int bh = flat >> 5;
  const int q0 = (flat & 31) * 32;
  const int b = bh >> 4, h = bh & 15;
  const int fr = lane & 15, fo = (lane >> 4) * 8, rb = (lane >> 4) * 4;

  for (int c = tid; c < 1024; c += 256)
    smask[c] = mask[b * LKc + c] ? -1e9f : 0.0f;

  // Q fragments from token-major q3: row t = lq*8+b, cols h*64 + ...
  bf16x8 qf[2][2];
  const bf16* Qb = q3 + ((size_t)q0 * Bc + b) * Ec + h * Dc;
#pragma unroll
  for (int m = 0; m < 2; ++m)
#pragma unroll
    for (int kc = 0; kc < 2; ++kc)
      qf[m][kc] = *reinterpret_cast<const bf16x8*>(
          Qb + (size_t)(m * 16 + fr) * (Bc * Ec) + kc * 32 + fo);
  __syncthreads();  // smask ready

  // ---- QK^T + exp + running sums; wave w owns cols [w*256, w*256+256) ----
  const bf16* Kb = k3 + (size_t)b * Ec + h * Dc;
  float s0[4] = {0.f, 0.f, 0.f, 0.f}, s1[4] = {0.f, 0.f, 0.f, 0.f};
  for (int t = 0; t < 16; ++t) {
    const int n = (wave * 16 + t) * 16;
    const bf16* kp = Kb + (size_t)(n + fr) * (Bc * Ec) + fo;
    const bf16x8 kf0 = *reinterpret_cast<const bf16x8*>(kp);
    const bf16x8 kf1 = *reinterpret_cast<const bf16x8*>(kp + 32);
    f32x4 c0 = {}, c1 = {};
    c0 = MFMA16(qf[0][0], kf0, c0);
    c0 = MFMA16(qf[0][1], kf1, c0);
    c1 = MFMA16(qf[1][0], kf0, c1);
    c1 = MFMA16(qf[1][1], kf1, c1);
    const int col = n + fr;
    const float madd = smask[col];
#pragma unroll
    for (int r = 0; r < 4; ++r) {
      const float e0 = __expf(c0[r] + madd);
      const float e1 = __expf(c1[r] + madd);
      s0[r] += e0; s1[r] += e1;
      sP[rb + r][col]      = (bf16)e0;
      sP[16 + rb + r][col] = (bf16)e1;
    }
  }
#pragma unroll
  for (int o = 1; o < 16; o <<= 1)
#pragma unroll
    for (int r = 0; r < 4; ++r) {
      s0[r] += __shfl_xor(s0[r], o, 64);
      s1[r] += __shfl_xor(s1[r], o, 64);
    }
  if (fr == 0) {
#pragma unroll
    for (int r = 0; r < 4; ++r) {
      psum[wave][rb + r]      = s0[r];
      psum[wave][16 + rb + r] = s1[r];
    }
  }
  __syncthreads();
  if (tid < 32)
    rinv[tid] = 1.0f / (psum[0][tid] + psum[1][tid] + psum[2][tid] + psum[3][tid]);
  __syncthreads();

  // ---- f32 prob write: p = e * rinv (coalesced 4KB rows) ----
  float* ap = attn_out + ((size_t)bh * LQc + q0) * LKc;
  for (int r = 0; r < 32; ++r) {
    const float rs = rinv[r];
    const bf16x4 v = *reinterpret_cast<const bf16x4*>(&sP[r][tid * 4]);
    f32x4 p;
    p.x = (float)v.x * rs; p.y = (float)v.y * rs;
    p.z = (float)v.z * rs; p.w = (float)v.w * rs;
    *reinterpret_cast<f32x4*>(ap + (size_t)r * LKc + tid * 4) = p;
  }

  // ---- PV on unnormalized e; wave w owns d-cols [w*16, w*16+16) ----
  const bf16* Vb = VhT + ((size_t)bh * Dc + wave * 16 + fr) * LKc;
  f32x4 cacc0 = {}, cacc1 = {};
  for (int kc = 0; kc < 1024; kc += 32) {
    const bf16x8 vf  = *reinterpret_cast<const bf16x8*>(Vb + kc + fo);
    const bf16x8 pa0 = *reinterpret_cast<const bf16x8*>(&sP[fr][kc + fo]);
    const bf16x8 pa1 = *reinterpret_cast<const bf16x8*>(&sP[16 + fr][kc + fo]);
    cacc0 = MFMA16(pa0, vf, cacc0);
    cacc1 = MFMA16(pa1, vf, cacc1);
  }
  const int e = h * Dc + wave * 16 + fr;
#pragma unroll
  for (int r = 0; r < 4; ++r) {
    const int qa = q0 + rb + r;
    ctx_out[((size_t)qa * Bc + b) * Ec + e] = (bf16)(cacc0[r] * rinv[rb + r]);
    const int qb2 = q0 + 16 + rb + r;
    ctx_out[((size_t)qb2 * Bc + b) * Ec + e] = (bf16)(cacc1[r] * rinv[16 + rb + r]);
  }
}

// ============================================================================
extern "C" void kernel_launch(void* const* d_in, const int* in_sizes, int n_in,
                              void* d_out, int out_size, void* d_ws, size_t ws_size,
                              hipStream_t stream) {
  const float* query = (const float*)d_in[0];
  const float* keyx  = (const float*)d_in[1];
  const int*   mask  = (const int*)d_in[2];
  const float* wq    = (const float*)d_in[3];
  const float* wkv   = (const float*)d_in[4];
  const float* wout  = (const float*)d_in[5];

  float* out  = (float*)d_out;                  // (LQ,B,E) flat
  float* attn = out + (size_t)LQc * Bc * Ec;    // (B,H,LQ,LK) flat

  bf16* cvt   = (bf16*)d_ws;
  bf16* q2    = cvt;                    // 8,388,608 (pre-scaled by 0.125)
  bf16* k2    = q2   + 8388608;         // 8,388,608
  bf16* wqb   = k2   + 8388608;         // 1,048,576
  bf16* wkvb  = wqb  + 1048576;         // 2,097,152
  bf16* woutb = wkvb + 2097152;         // 1,048,576
  bf16* q3    = woutb + 1048576;        // 8,388,608 token-major
  bf16* k3    = q3   + 8388608;         // 8,388,608 token-major
  bf16* v3    = k3   + 8388608;         // 8,388,608 token-major
  bf16* vt    = q2;                     // alias: q2 dead after proj gemm
  bf16* ctx   = k2;                     // alias: k2 dead after proj gemm

  k_convert<<<10240, 256, 0, stream>>>(query, keyx, wq, wkv, wout, cvt);
  k_gemm<0><<<1536, 256, 0, stream>>>(q2, k2, wqb, wkvb, q3, k3, v3, nullptr);
  k_vtrans<<<dim3(16, 128), 256, 0, stream>>>(v3, vt);
  k_attn<<<4096, 256, 0, stream>>>(q3, k3, vt, mask, attn, ctx);
  k_gemm<2><<<512, 256, 0, stream>>>(ctx, nullptr, woutb, nullptr, nullptr, nullptr, nullptr, out);
}